// Round 3
// baseline (679.817 us; speedup 1.0000x reference)
//
#include <hip/hip_runtime.h>
#include <hip/hip_bf16.h>

// BayesianKAN_ECG: x[65536,1000] f32 -> pool10 -> norm(ddof=1) -> KAN1(RBF16,
// 100->64) -> tanh -> norm -> KAN2(RBF16, 64->5) -> OUT FP32 [65536,5].
// Fused single kernel: 64 rows/block, 256 thr, bf16 MFMA 16x16x32 both layers.
// NOTE: output dtype is fp32 (reference returns float32). R1/R2 failed only
// because they stored bf16 into the fp32 buffer (identical absmax 2.789 from
// two independent implementations proved the math correct).

#define SEQ    1000
#define INDIM  100
#define HID    64
#define OUTD   5
#define NB     16
#define ROWS   64
#define NTHR   256

typedef __bf16 v8bf __attribute__((ext_vector_type(8)));
typedef float  v4f  __attribute__((ext_vector_type(4)));

// LDS layout (bytes):
//  region1 @0      : xn[64][101] f32 (25,856)  -> later reused as hbuf[64][65] f32 (16,640)
//  region2 @25856  : phase1: c1c[64][168] bf16 (21,504) + b1c[64][168] bf16 (21,504)
//                    phase2: c2b[16][1032] bf16 (33,024) + b2c[64][136] bf16 (17,408)
//  centers @76288  : f32[16]
// total 76,352 B -> 2 blocks/CU
#define R2_OFF  25856
#define B1C_OFF (R2_OFF + 21504)
#define B2C_OFF (R2_OFF + 33024)
#define CEN_OFF 76288
#define SM_BYTES 76352

__global__ __launch_bounds__(NTHR, 2) void kan_fused(
    const float* __restrict__ x, const float* __restrict__ c1,
    const float* __restrict__ c2, const float* __restrict__ cen,
    float* __restrict__ out)
{
  __shared__ __align__(16) unsigned char sm[SM_BYTES];
  float*  xn  = (float*)sm;                    // stride 101
  float*  hb  = (float*)sm;                    // stride 65 (aliases xn after KAN1)
  __bf16* c1c = (__bf16*)(sm + R2_OFF);        // stride 168
  __bf16* b1c = (__bf16*)(sm + B1C_OFF);       // stride 168
  __bf16* c2b = (__bf16*)(sm + R2_OFF);        // stride 1032 (aliases c1c, phase 2)
  __bf16* b2c = (__bf16*)(sm + B2C_OFF);       // stride 136
  float*  scen = (float*)(sm + CEN_OFF);

  const int tid  = threadIdx.x;
  const int row0 = blockIdx.x * ROWS;
  if (tid < NB) scen[tid] = cen[tid];

  const float kC = -(0.5f / 0.36f);

  // ---- pool: mean over 10 consecutive -> xn[r][i] ----
  #pragma unroll
  for (int it = 0; it < 25; ++it) {
    int idx = tid + it * NTHR;                 // < 6400
    int r = idx / 100, i = idx - r * 100;
    const float2* xp = (const float2*)(x + (size_t)(row0 + r) * SEQ + i * 10);
    float s = 0.f;
    #pragma unroll
    for (int j = 0; j < 5; ++j) { float2 v = xp[j]; s += v.x + v.y; }
    xn[r * 101 + i] = s * 0.1f;
  }
  __syncthreads();

  // ---- per-row normalize over 100 (ddof=1, sd+1e-6) ----
  if (tid < ROWS) {
    float s = 0.f;
    for (int j = 0; j < INDIM; ++j) s += xn[tid * 101 + j];
    float mu = s * (1.f / INDIM);
    float v = 0.f;
    for (int j = 0; j < INDIM; ++j) { float d = xn[tid * 101 + j] - mu; v += d * d; }
    float rs = 1.f / (sqrtf(v * (1.f / (INDIM - 1))) + 1e-6f);
    for (int j = 0; j < INDIM; ++j) xn[tid * 101 + j] = (xn[tid * 101 + j] - mu) * rs;
  }
  __syncthreads();

  const int lane = tid & 63, wv = tid >> 6;    // 4 waves, wave wv owns rows wv*16..+15
  const int l15  = lane & 15, q = lane >> 4;

  // ---- KAN1: h[64r][64o] = sum_k basis(xn)[r][k] * c1[o][k], K=1600 in 10 chunks ----
  v4f acc[4];
  #pragma unroll
  for (int f = 0; f < 4; ++f) acc[f] = (v4f){0.f, 0.f, 0.f, 0.f};

  for (int c = 0; c < 10; ++c) {
    // stage c1 chunk: 64 o x 160 k (coalesced, fp32->bf16)
    #pragma unroll
    for (int it = 0; it < 40; ++it) {
      int idx = tid + it * NTHR;               // < 10240
      int o = idx / 160, kk = idx - o * 160;
      c1c[o * 168 + kk] = (__bf16)c1[(size_t)o * 1600 + c * 160 + kk];
    }
    // basis chunk: 64 r x (10 i x 16 n)
    #pragma unroll
    for (int it = 0; it < 40; ++it) {
      int idx = tid + it * NTHR;
      int r = idx / 160, rem = idx - r * 160;
      int il = rem >> 4, n = rem & 15;
      float d = xn[r * 101 + c * 10 + il] - scen[n];
      b1c[r * 168 + rem] = (__bf16)__expf(d * d * kC);
    }
    __syncthreads();
    const int ar = wv * 16 + l15;
    #pragma unroll
    for (int ks = 0; ks < 5; ++ks) {
      v8bf a = *(const v8bf*)&b1c[ar * 168 + ks * 32 + q * 8];
      #pragma unroll
      for (int f = 0; f < 4; ++f) {
        v8bf b = *(const v8bf*)&c1c[(f * 16 + l15) * 168 + ks * 32 + q * 8];
        acc[f] = __builtin_amdgcn_mfma_f32_16x16x32_bf16(a, b, acc[f], 0, 0, 0);
      }
    }
    __syncthreads();
  }

  // ---- tanh -> hbuf (D layout: row=(lane>>4)*4+reg, col=lane&15) ----
  #pragma unroll
  for (int f = 0; f < 4; ++f) {
    #pragma unroll
    for (int rg = 0; rg < 4; ++rg) {
      int r = wv * 16 + q * 4 + rg;
      hb[r * 65 + f * 16 + l15] = tanhf(acc[f][rg]);
    }
  }
  __syncthreads();

  // ---- per-row normalize h over 64 (ddof=1); stage c2 (rows>=5 zero) ----
  if (tid < ROWS) {
    float s = 0.f;
    for (int j = 0; j < HID; ++j) s += hb[tid * 65 + j];
    float mu = s * (1.f / HID);
    float v = 0.f;
    for (int j = 0; j < HID; ++j) { float d = hb[tid * 65 + j] - mu; v += d * d; }
    float rs = 1.f / (sqrtf(v * (1.f / (HID - 1))) + 1e-6f);
    for (int j = 0; j < HID; ++j) hb[tid * 65 + j] = (hb[tid * 65 + j] - mu) * rs;
  }
  #pragma unroll
  for (int it = 0; it < 64; ++it) {
    int idx = tid + it * NTHR;                 // < 16384
    int o = idx >> 10, k = idx & 1023;
    c2b[o * 1032 + k] = (o < OUTD) ? (__bf16)c2[(size_t)o * 1024 + k] : (__bf16)0.f;
  }
  __syncthreads();

  // ---- KAN2: out[64r][5] via MFMA (N padded to 16), K=1024 in 8 chunks ----
  v4f acc2 = (v4f){0.f, 0.f, 0.f, 0.f};
  for (int c = 0; c < 8; ++c) {
    #pragma unroll
    for (int it = 0; it < 32; ++it) {
      int idx = tid + it * NTHR;               // < 8192
      int r = idx >> 7, kk = idx & 127;
      int i2 = c * 8 + (kk >> 4), n = kk & 15;
      float d = hb[r * 65 + i2] - scen[n];
      b2c[r * 136 + kk] = (__bf16)__expf(d * d * kC);
    }
    __syncthreads();
    #pragma unroll
    for (int ks = 0; ks < 4; ++ks) {
      v8bf a = *(const v8bf*)&b2c[(wv * 16 + l15) * 136 + ks * 32 + q * 8];
      v8bf b = *(const v8bf*)&c2b[l15 * 1032 + c * 128 + ks * 32 + q * 8];
      acc2 = __builtin_amdgcn_mfma_f32_16x16x32_bf16(a, b, acc2, 0, 0, 0);
    }
    __syncthreads();
  }

  // ---- FP32 store (output dtype = reference output dtype = float32) ----
  if (l15 < OUTD) {
    #pragma unroll
    for (int rg = 0; rg < 4; ++rg) {
      int r = row0 + wv * 16 + q * 4 + rg;
      out[(size_t)r * OUTD + l15] = acc2[rg];
    }
  }
}

extern "C" void kernel_launch(void* const* d_in, const int* in_sizes, int n_in,
                              void* d_out, int out_size, void* d_ws, size_t ws_size,
                              hipStream_t stream) {
  const float* x   = (const float*)d_in[0];
  const float* c1  = (const float*)d_in[1];
  const float* c2  = (const float*)d_in[2];
  const float* cen = (const float*)d_in[3];
  float* out = (float*)d_out;
  dim3 grid(65536 / ROWS), block(NTHR);
  hipLaunchKernelGGL(kan_fused, grid, block, 0, stream, x, c1, c2, cen, out);
}

// Round 5
// 421.797 us; speedup vs baseline: 1.6117x; 1.6117x over previous
//
#include <hip/hip_runtime.h>
#include <hip/hip_bf16.h>

// BayesianKAN_ECG: x[65536,1000] f32 -> pool10 -> norm(ddof=1) -> KAN1(RBF16,
// 100->64) -> tanh -> norm -> KAN2(RBF16, 64->5) -> fp32 out [65536,5].
// R5 = R4 with the c1c staging bug fixed (was staging 10 quads/row, need 20:
// chunk row = 160 bf16 = 20 uint4). R3 baseline: 433 us (occ 24%, VALU 13.6%).

#define SEQ    1000
#define INDIM  100
#define HID    64
#define OUTD   5
#define NB     16
#define ROWS   64
#define NTHR   512

typedef __bf16 v8bf __attribute__((ext_vector_type(8)));
typedef float  v4f  __attribute__((ext_vector_type(4)));

// LDS layout (bytes), total 76,352 -> 2 blocks/CU:
//  [0,25856)      xn f32 [64][101]; later hb f32 [64][65] @0 + red f32 [64][17] @16640
//  [25856,68864)  phase1: c1c bf16 [64][168] @25856, b1c bf16 [64][168] @47360
//                 phase2: c2s bf16 [16][1032] @25856, b2c bf16 [64][136] @58880
//  [76288]        centers f32[16]
#define RED_OFF 16640
#define R2_OFF  25856
#define B1C_OFF 47360
#define B2C_OFF 58880
#define CEN_OFF 76288
#define SM_BYTES 76352

// ---- pre-kernel: convert c1 -> bf16 [64][1600], c2 -> bf16 [16][1024] (rows>=5 zero)
__global__ __launch_bounds__(256) void cvt_w(
    const float* __restrict__ c1, const float* __restrict__ c2,
    __bf16* __restrict__ c1b, __bf16* __restrict__ c2b)
{
  int t = blockIdx.x * 256 + threadIdx.x;
  if (t < 25600) {                       // c1: 102,400 elems = 25,600 quads
    float4 v = ((const float4*)c1)[t];
    __bf16* d = c1b + t * 4;
    d[0] = (__bf16)v.x; d[1] = (__bf16)v.y; d[2] = (__bf16)v.z; d[3] = (__bf16)v.w;
  }
  if (t < 4096) {                        // c2 padded: 16x1024 = 4,096 quads
    int o = t >> 8;                      // 256 quads per 1024-elem row
    __bf16* d = c2b + t * 4;
    if (o < OUTD) {
      float4 v = ((const float4*)c2)[t];
      d[0] = (__bf16)v.x; d[1] = (__bf16)v.y; d[2] = (__bf16)v.z; d[3] = (__bf16)v.w;
    } else {
      d[0] = (__bf16)0.f; d[1] = (__bf16)0.f; d[2] = (__bf16)0.f; d[3] = (__bf16)0.f;
    }
  }
}

__global__ __launch_bounds__(NTHR, 2) void kan_main(
    const float* __restrict__ x, const __bf16* __restrict__ c1b,
    const __bf16* __restrict__ c2bw, const float* __restrict__ cen,
    float* __restrict__ out)
{
  __shared__ __align__(16) unsigned char sm[SM_BYTES];
  float*  xn  = (float*)sm;                    // stride 101
  float*  hb  = (float*)sm;                    // stride 65
  float*  red = (float*)(sm + RED_OFF);        // stride 17
  __bf16* c1c = (__bf16*)(sm + R2_OFF);        // stride 168
  __bf16* b1c = (__bf16*)(sm + B1C_OFF);       // stride 168
  __bf16* c2s = (__bf16*)(sm + R2_OFF);        // stride 1032
  __bf16* b2c = (__bf16*)(sm + B2C_OFF);       // stride 136
  float*  scen = (float*)(sm + CEN_OFF);

  const int tid  = threadIdx.x;
  const int row0 = blockIdx.x * ROWS;
  if (tid < NB) scen[tid] = cen[tid];

  const float kC = -(0.5f / 0.36f);
  const int w = tid >> 6, lane = tid & 63;
  const int l15 = lane & 15, q = lane >> 4;

  // ---- pool: mean over 10 -> xn[r][i] ----
  #pragma unroll
  for (int it = 0; it < 13; ++it) {
    int idx = tid + it * NTHR;
    if (idx < 6400) {
      int r = idx / 100, i = idx - r * 100;
      const float2* xp = (const float2*)(x + (size_t)(row0 + r) * SEQ + i * 10);
      float s = 0.f;
      #pragma unroll
      for (int j = 0; j < 5; ++j) { float2 v = xp[j]; s += v.x + v.y; }
      xn[r * 101 + i] = s * 0.1f;
    }
  }
  __syncthreads();

  // ---- norm x: wave-parallel, 8 waves x 8 rows, shuffle reduce ----
  #pragma unroll
  for (int rr = 0; rr < 8; ++rr) {
    int r = w * 8 + rr;
    float v0 = xn[r * 101 + lane];                              // lane < 64 < 100
    float v1 = (lane < 36) ? xn[r * 101 + 64 + lane] : 0.f;
    float s = v0 + v1, s2 = v0 * v0 + v1 * v1;
    #pragma unroll
    for (int m = 32; m; m >>= 1) { s += __shfl_xor(s, m, 64); s2 += __shfl_xor(s2, m, 64); }
    float mu = s * (1.f / INDIM);
    float var = (s2 - INDIM * mu * mu) * (1.f / (INDIM - 1));
    float rs = 1.f / (sqrtf(fmaxf(var, 0.f)) + 1e-6f);
    xn[r * 101 + lane] = (v0 - mu) * rs;
    if (lane < 36) xn[r * 101 + 64 + lane] = (v1 - mu) * rs;
  }
  __syncthreads();

  // ---- KAN1: h[64r][64o], K=1600 in 10 chunks of 160 ----
  const int g = w >> 1;              // MFMA row group (16 rows)
  const int fh = (w & 1) * 2;        // col-block pair {fh, fh+1}
  v4f acc[2];
  acc[0] = (v4f){0.f,0.f,0.f,0.f}; acc[1] = (v4f){0.f,0.f,0.f,0.f};

  for (int c = 0; c < 10; ++c) {
    // stage c1 chunk: 64 o x 160 k bf16 = 64 x 20 uint4 = 1280 quads
    #pragma unroll
    for (int it = 0; it < 3; ++it) {
      int id2 = tid + it * NTHR;
      if (id2 < 1280) {
        int o = id2 / 20, k16 = id2 - o * 20;
        uint4 v = *(const uint4*)(c1b + (size_t)o * 1600 + c * 160 + k16 * 8);
        *(uint4*)(c1c + o * 168 + k16 * 8) = v;
      }
    }
    // basis chunk: 64 r x 160 (10 i x 16 n), paired bf16 writes
    #pragma unroll
    for (int it = 0; it < 10; ++it) {
      int idx = tid + it * NTHR;              // < 5120 pairs
      int r = idx / 80, pp = idx - r * 80;
      int i = pp >> 3, n = (pp & 7) * 2;
      float xv = xn[r * 101 + c * 10 + i];
      float d0 = xv - scen[n], d1 = xv - scen[n + 1];
      __hip_bfloat162 h2;
      h2.x = __float2bfloat16(__expf(d0 * d0 * kC));
      h2.y = __float2bfloat16(__expf(d1 * d1 * kC));
      *(__hip_bfloat162*)(b1c + r * 168 + pp * 2) = h2;
    }
    __syncthreads();
    const int ar = g * 16 + l15;
    #pragma unroll
    for (int ks = 0; ks < 5; ++ks) {
      v8bf a = *(const v8bf*)&b1c[ar * 168 + ks * 32 + q * 8];
      #pragma unroll
      for (int ff = 0; ff < 2; ++ff) {
        v8bf b = *(const v8bf*)&c1c[((fh + ff) * 16 + l15) * 168 + ks * 32 + q * 8];
        acc[ff] = __builtin_amdgcn_mfma_f32_16x16x32_bf16(a, b, acc[ff], 0, 0, 0);
      }
    }
    __syncthreads();
  }

  // ---- tanh -> hb (D: row=q*4+rg, col=l15) ----
  #pragma unroll
  for (int ff = 0; ff < 2; ++ff) {
    #pragma unroll
    for (int rg = 0; rg < 4; ++rg) {
      float t = acc[ff][rg];
      float e = __expf(2.f * t);                 // tanh = 1 - 2/(e^{2t}+1)
      hb[(g * 16 + q * 4 + rg) * 65 + (fh + ff) * 16 + l15] = 1.f - 2.f / (e + 1.f);
    }
  }
  __syncthreads();

  // ---- norm h: wave-parallel (8 waves x 8 rows, 64 elems = 64 lanes) ----
  #pragma unroll
  for (int rr = 0; rr < 8; ++rr) {
    int r = w * 8 + rr;
    float v = hb[r * 65 + lane];
    float s = v, s2 = v * v;
    #pragma unroll
    for (int m = 32; m; m >>= 1) { s += __shfl_xor(s, m, 64); s2 += __shfl_xor(s2, m, 64); }
    float mu = s * (1.f / HID);
    float var = (s2 - HID * mu * mu) * (1.f / (HID - 1));
    float rs = 1.f / (sqrtf(fmaxf(var, 0.f)) + 1e-6f);
    hb[r * 65 + lane] = (v - mu) * rs;
  }
  // stage c2s: 16x1024 bf16 = 2048 x 16B (region2 free after last KAN1 sync)
  #pragma unroll
  for (int it = 0; it < 4; ++it) {
    int idx = tid + it * NTHR;                  // < 2048
    int o = idx >> 7, k16 = idx & 127;
    uint4 v = *(const uint4*)(c2bw + o * 1024 + k16 * 8);
    *(uint4*)(c2s + o * 1032 + k16 * 8) = v;
  }
  __syncthreads();

  // ---- KAN2: out[64r][16(5)], K=1024 in 8 chunks; wave pairs split K ----
  v4f acc2 = (v4f){0.f,0.f,0.f,0.f};
  for (int c = 0; c < 8; ++c) {
    #pragma unroll
    for (int it = 0; it < 8; ++it) {
      int idx = tid + it * NTHR;                // < 4096 pairs
      int r = idx >> 6, pp = idx & 63;          // 64 pairs per row (8 i x 8)
      int i = pp >> 3, n = (pp & 7) * 2;
      float hv = hb[r * 65 + c * 8 + i];
      float d0 = hv - scen[n], d1 = hv - scen[n + 1];
      __hip_bfloat162 h2;
      h2.x = __float2bfloat16(__expf(d0 * d0 * kC));
      h2.y = __float2bfloat16(__expf(d1 * d1 * kC));
      *(__hip_bfloat162*)(b2c + r * 136 + pp * 2) = h2;
    }
    __syncthreads();
    #pragma unroll
    for (int kk = 0; kk < 2; ++kk) {
      int ks = (w & 1) * 2 + kk;
      v8bf a = *(const v8bf*)&b2c[(g * 16 + l15) * 136 + ks * 32 + q * 8];
      v8bf b = *(const v8bf*)&c2s[l15 * 1032 + c * 128 + ks * 32 + q * 8];
      acc2 = __builtin_amdgcn_mfma_f32_16x16x32_bf16(a, b, acc2, 0, 0, 0);
    }
    __syncthreads();
  }

  // ---- combine wave-pair K halves, store fp32 ----
  if (w & 1) {
    #pragma unroll
    for (int rg = 0; rg < 4; ++rg)
      red[(g * 16 + q * 4 + rg) * 17 + l15] = acc2[rg];
  }
  __syncthreads();
  if (!(w & 1) && l15 < OUTD) {
    #pragma unroll
    for (int rg = 0; rg < 4; ++rg) {
      int r = g * 16 + q * 4 + rg;
      out[(size_t)(row0 + r) * OUTD + l15] = acc2[rg] + red[r * 17 + l15];
    }
  }
}

extern "C" void kernel_launch(void* const* d_in, const int* in_sizes, int n_in,
                              void* d_out, int out_size, void* d_ws, size_t ws_size,
                              hipStream_t stream) {
  const float* x   = (const float*)d_in[0];
  const float* c1  = (const float*)d_in[1];
  const float* c2  = (const float*)d_in[2];
  const float* cen = (const float*)d_in[3];
  float* out = (float*)d_out;

  __bf16* c1b = (__bf16*)d_ws;                         // 204,800 B
  __bf16* c2b = (__bf16*)((char*)d_ws + 204800);       //  32,768 B

  hipLaunchKernelGGL(cvt_w, dim3(100), dim3(256), 0, stream, c1, c2, c1b, c2b);
  hipLaunchKernelGGL(kan_main, dim3(65536 / ROWS), dim3(NTHR), 0, stream,
                     x, c1b, c2b, cen, out);
}